// Round 8
// baseline (320.554 us; speedup 1.0000x reference)
//
#include <hip/hip_runtime.h>

// CfCHead: B=64, S=2048, H=1024 sequential nonlinear scan. Round-8:
// TWO-STAGE WAVE PIPELINE - split the serial state across waves so two
// active waves per SIMD co-issue and fill each other's transcendental
// stalls (r3/r7 fixed point: 1 busy wave/SIMD = 186 busy cyc/step, 23% idle;
// trans-pipe throughput alone would be ~80).
//  - waves 0-3 (stage-1): x-only gates + the self-contained n-recurrence
//    (6 trans/step). Streams f_t, i_t*g_t, 0.01*o_t to LDS (no reg arrays).
//  - waves 4-7 (stage-2, lag 1 chunk): Il(lambda), sigmoid(c), h-recurrence
//    (4 trans/step), writes h to LDS, and (lag 2) the r6 register-pw reduce.
//  - all LDS: stride-17 float SoA b32 (measured 0 conflicts in r3/r6/r7).
//  - math byte-identical to r7 (CUP drift table, CREB rebase, HW exp/rcp -
//    r6 proved polys lose).
// One barrier per 16-step chunk; 128-chunk pipeline + 2 flush iterations.

#define Bv   64
#define Sv   2048
#define Hv   1024
#define TPB  256
#define NT   512
#define CH   16
#define NCH  (Sv / CH)      /* 128 */
#define STR  17
#define ROWS (TPB * STR)    /* 4352 floats per buffer */

#define L2E   1.44269504088896340736f
#define NL2E (-1.44269504088896340736f)
#define LN2   0.69314718055994530942f
#define KNU   0.014426950408889634f     /* 0.01*L2E  */
#define CREB  0.692493619626702435f     /* 16*0.03*L2E */
#define LOG2_001 (-6.6438561897747247f) /* log2(0.01) */

__device__ __forceinline__ float fexp2(float x) { return __builtin_amdgcn_exp2f(x); }
__device__ __forceinline__ float frcp(float x)  { return __builtin_amdgcn_rcpf(x); }

// out[b*S*2 + t*2 + k] = proj_b[k]  (clears 0xAA poison; scan atomically adds)
__global__ __launch_bounds__(256) void init_out(const float* __restrict__ proj_b,
                                                float* __restrict__ out) {
    int i = blockIdx.x * 256 + threadIdx.x;
    out[i] = proj_b[i & 1];
}

__global__ __launch_bounds__(NT, 1) void cfc_scan(
    const float* __restrict__ x_codes,
    const float* __restrict__ Wi_w, const float* __restrict__ Wi_b,
    const float* __restrict__ Wf_w, const float* __restrict__ Wf_b,
    const float* __restrict__ Wo_w, const float* __restrict__ Wo_b,
    const float* __restrict__ Wg_w, const float* __restrict__ Wg_b,
    const float* __restrict__ Wl_w, const float* __restrict__ Wl_b,
    const float* __restrict__ proj_w,
    const float* __restrict__ n_init,
    float* __restrict__ out)
{
    // stage-1 -> stage-2 transport (P = i*g scaled, F = f, O = 0.01*o) and h,
    // all double-buffered. 4 arrays * 2 * 4352 * 4 B = 139,264 B LDS.
    __shared__ float Pb[2][ROWS];
    __shared__ float Fb[2][ROWS];
    __shared__ float Ob[2][ROWS];
    __shared__ float Hb[2][ROWS];

    const int b   = blockIdx.x >> 2;
    const int q   = blockIdx.x & 3;
    const int tid = threadIdx.x;
    const int ct  = tid - TPB;           // stage-2 local id

    const float* __restrict__ xrow = x_codes + b * Sv;
    float* __restrict__ orow = out + b * (Sv * 2);

    // ---- stage-1 setup (waves 0-3): gates + n-chain ----
    float wi2 = 0, bi2 = 0, wf2 = 0, bf2 = 0, wo2 = 0, bo2 = 0;
    float wg2 = 0, bg2 = 0;
    float m = 0, En = 0;
    // ---- stage-2 setup (waves 4-7): lambda + c/h-chain + reduce ----
    float wl2 = 0, bl2 = 0;
    float C = 0, h = 0;
    float pwreg[32];
    int   rk = 0, rt = 0, rseg = 0;

    if (tid < TPB) {
        const int j = q * TPB + tid;
        const float wi = Wi_w[j], bi = Wi_b[j];
        const float wf = Wf_w[j], bf = Wf_b[j];
        const float wo = Wo_w[j], bo = Wo_b[j];
        const float wg = Wg_w[j], bg = Wg_b[j];
        wi2 = wi * KNU;  bi2 = fmaf(-0.65f, wi, bi) * L2E;
        wf2 = wf * KNU;  bf2 = fmaf(-0.65f, wf, bf) * L2E;
        wo2 = wo * KNU;  bo2 = fmaf(-0.65f, wo, bo) * L2E + LOG2_001;
        wg2 = -wg * KNU; bg2 = fmaf(-0.65f, wg, bg) * NL2E;
        m  = n_init[j] * NL2E;   // m = -n*L2E (drift accumulated via CREB)
        En = fexp2(m);           // e^{-n}
    } else {
        const int j = q * TPB + ct;
        const float wl = Wl_w[j], bl = Wl_b[j];
        wl2 = -wl * KNU; bl2 = fmaf(-0.65f, wl, bl) * NL2E;
        rk   = (ct >> 7) & 1;
        rt   = (ct >> 3) & 15;
        rseg = ct & 7;
        const float* __restrict__ pwsrc = proj_w + rk * Hv + q * TPB;
        #pragma unroll
        for (int i2 = 0; i2 < 32; ++i2) {
            const int jj = rseg * 32 + ((i2 + 4 * rseg) & 31);
            pwreg[i2] = pwsrc[jj];
        }
    }

    // 2^{0.03*L2E*u} = e^{0.03u}: within-chunk drift of e^{-n}
    static const float CUP[CH] = {
        1.0f,        1.03045453f, 1.06183655f, 1.09417428f,
        1.12749685f, 1.16183424f, 1.19721736f, 1.23367806f,
        1.27124915f, 1.30996445f, 1.34985881f, 1.39096813f,
        1.43332941f, 1.47698079f, 1.52196156f, 1.56831219f };

    // Pipeline: region c -> stage-1 builds chunk c; stage-2 builds h for
    // chunk c-1; reduce emits chunk c-2. One barrier per region.
    for (int c = 0; c < NCH + 2; ++c) {
        if (tid < TPB) {
            if (c < NCH) {
                const int t0 = c * CH;
                float* __restrict__ Pp = &Pb[c & 1][tid * STR];
                float* __restrict__ Fp = &Fb[c & 1][tid * STR];
                float* __restrict__ Op = &Ob[c & 1][tid * STR];
                #pragma unroll
                for (int u = 0; u < CH; ++u) {
                    const float xc  = xrow[t0 + u];
                    const float Gi  = fexp2(fmaf(xc, wi2, bi2));  // e^{pre_i}
                    const float Gf  = fexp2(fmaf(xc, wf2, bf2));  // e^{pre_f}
                    const float Goa = fexp2(fmaf(xc, wo2, bo2));  // .01 e^{pre_o}
                    const float eg  = fexp2(fmaf(xc, wg2, bg2));  // e^{-pre_g}
                    const float Gg  = frcp(fmaf(eg, -LN2, -LN2)); // -L2E*sig(g)
                    const float Enu = (u == 0) ? En : En * CUP[u];
                    Fp[u] = Gf * Enu;                  // f_t
                    Pp[u] = (Gi * Gg) * Enu;           // -L2E * i_t * g_t
                    Op[u] = Goa * Enu;                 // 0.01 * o_t
                    const float Gs = fmaf(Goa, 100.0f, Gi + Gf);
                    m = fmaf(Gs * Enu, -KNU, m);
                    if (u == CH - 1) m += CREB;        // drift rebase
                    En = fexp2(m);
                }
            }
        } else {
            if (c >= 1 && c <= NCH) {
                const int d  = c - 1;
                const int t0 = d * CH;
                const float* __restrict__ Pp = &Pb[d & 1][ct * STR];
                const float* __restrict__ Fp = &Fb[d & 1][ct * STR];
                const float* __restrict__ Op = &Ob[d & 1][ct * STR];
                float* __restrict__ Hp = &Hb[d & 1][ct * STR];
                #pragma unroll
                for (int u = 0; u < CH; ++u) {
                    const float xc = xrow[t0 + u];
                    const float el = fexp2(fmaf(xc, wl2, bl2));   // e^{-pre_l}
                    const float Il = fmaf(frcp(el + 1.01f), -0.01f, 1.0f);
                    C = fmaf(Fp[u], C, Pp[u]);          // C = -L2E*c
                    const float sc = frcp(1.0f + fexp2(C));  // sigmoid(c)
                    h = fmaf(Op[u], sc, h) * Il;
                    Hp[u] = h;
                }
            }
            if (c >= 2) {
                const int e  = c - 2;
                const float* __restrict__ hb = &Hb[e & 1][0];
                float sum = 0.0f;
                #pragma unroll
                for (int i2 = 0; i2 < 32; ++i2) {
                    const int jj = rseg * 32 + ((i2 + 4 * rseg) & 31);
                    sum = fmaf(hb[jj * STR + rt], pwreg[i2], sum);
                }
                sum += __shfl_xor(sum, 1, 64);
                sum += __shfl_xor(sum, 2, 64);
                sum += __shfl_xor(sum, 4, 64);
                if (rseg == 0) atomicAdd(&orow[(e * CH + rt) * 2 + rk], sum);
            }
        }
        __syncthreads();
    }
}

extern "C" void kernel_launch(void* const* d_in, const int* in_sizes, int n_in,
                              void* d_out, int out_size, void* d_ws, size_t ws_size,
                              hipStream_t stream) {
    const float* x_codes = (const float*)d_in[0];
    const float* Wi_w = (const float*)d_in[1];
    const float* Wi_b = (const float*)d_in[2];
    const float* Wf_w = (const float*)d_in[3];
    const float* Wf_b = (const float*)d_in[4];
    const float* Wo_w = (const float*)d_in[5];
    const float* Wo_b = (const float*)d_in[6];
    const float* Wg_w = (const float*)d_in[7];
    const float* Wg_b = (const float*)d_in[8];
    const float* Wl_w = (const float*)d_in[9];
    const float* Wl_b = (const float*)d_in[10];
    const float* proj_w = (const float*)d_in[11];
    const float* proj_b = (const float*)d_in[12];
    const float* n_init = (const float*)d_in[13];
    float* out = (float*)d_out;

    init_out<<<out_size / 256, 256, 0, stream>>>(proj_b, out);
    cfc_scan<<<Bv * (Hv / TPB), NT, 0, stream>>>(
        x_codes, Wi_w, Wi_b, Wf_w, Wf_b, Wo_w, Wo_b, Wg_w, Wg_b, Wl_w, Wl_b,
        proj_w, n_init, out);
}